// Round 1
// baseline (380.387 us; speedup 1.0000x reference)
//
#include <hip/hip_runtime.h>
#include <hip/hip_bf16.h>

#define N 8192
#define D 1024
#define BM 128
#define BN 128
#define BK 64

static constexpr float TEMP = 0.1f;
static constexpr float KEEP = 0.9f;
static constexpr float EPSN = 1e-8f;

typedef __attribute__((ext_vector_type(8))) short bf16x8;
typedef __attribute__((ext_vector_type(4))) float f32x4;

__device__ __forceinline__ void gload_lds16(const void* gsrc, void* ldst) {
  __builtin_amdgcn_global_load_lds(
      (const __attribute__((address_space(1))) void*)gsrc,
      (__attribute__((address_space(3))) void*)ldst, 16, 0, 0);
}

// ---------------- Kernel A: norms + diag + bf16 convert (scales folded) ----
// a_bf16[n][d] = inputs[n][d] / (max(||inputs[n]||,eps) * TEMP)
// b_bf16[n][d] = enhanced[n][d] / max(||enhanced[n]||,eps)
// diag[n]      = (inputs[n].enhanced[n]) / (na*nb*TEMP)   (fp32-exact)
struct bf4pack { __hip_bfloat16 v[4]; };

__global__ __launch_bounds__(256) void UCR_prep(
    const float* __restrict__ inputs, const float* __restrict__ noise,
    __hip_bfloat16* __restrict__ aB, __hip_bfloat16* __restrict__ bB,
    float* __restrict__ diag)
{
  const int row = blockIdx.x;
  const int t = threadIdx.x;
  const float4 x = ((const float4*)(inputs + (size_t)row * D))[t];
  const float4 u = ((const float4*)(noise  + (size_t)row * D))[t];
  const float inv_keep = 1.0f / KEEP;
  float4 e;
  e.x = (u.x < KEEP) ? x.x * inv_keep : 0.0f;
  e.y = (u.y < KEEP) ? x.y * inv_keep : 0.0f;
  e.z = (u.z < KEEP) ? x.z * inv_keep : 0.0f;
  e.w = (u.w < KEEP) ? x.w * inv_keep : 0.0f;

  float sx  = x.x*x.x + x.y*x.y + x.z*x.z + x.w*x.w;
  float se  = e.x*e.x + e.y*e.y + e.z*e.z + e.w*e.w;
  float sxe = x.x*e.x + x.y*e.y + x.z*e.z + x.w*e.w;

  #pragma unroll
  for (int off = 1; off < 64; off <<= 1) {
    sx  += __shfl_xor(sx, off);
    se  += __shfl_xor(se, off);
    sxe += __shfl_xor(sxe, off);
  }
  __shared__ float red[3][4];
  const int wid = t >> 6, lane = t & 63;
  if (lane == 0) { red[0][wid] = sx; red[1][wid] = se; red[2][wid] = sxe; }
  __syncthreads();
  sx  = red[0][0] + red[0][1] + red[0][2] + red[0][3];
  se  = red[1][0] + red[1][1] + red[1][2] + red[1][3];
  sxe = red[2][0] + red[2][1] + red[2][2] + red[2][3];

  const float na = fmaxf(sqrtf(sx), EPSN);
  const float nb = fmaxf(sqrtf(se), EPSN);
  const float sa = 1.0f / (na * TEMP);
  const float sb = 1.0f / nb;
  if (t == 0) diag[row] = sxe / (na * nb * TEMP);

  bf4pack pa, pb;
  pa.v[0] = __float2bfloat16(x.x * sa); pa.v[1] = __float2bfloat16(x.y * sa);
  pa.v[2] = __float2bfloat16(x.z * sa); pa.v[3] = __float2bfloat16(x.w * sa);
  pb.v[0] = __float2bfloat16(e.x * sb); pb.v[1] = __float2bfloat16(e.y * sb);
  pb.v[2] = __float2bfloat16(e.z * sb); pb.v[3] = __float2bfloat16(e.w * sb);
  ((bf4pack*)(aB + (size_t)row * D))[t] = pa;
  ((bf4pack*)(bB + (size_t)row * D))[t] = pb;
}

// ---------------- Kernel B: fused GEMM + exp + row-sum ---------------------
// logits[r][c] = sum_d aB[r][d]*bB[c][d]  (scales already folded)
// S[r] += sum_c exp(logits[r][c])  over this block's 128-column slab
__global__ __launch_bounds__(256) void UCR_gemm(
    const __hip_bfloat16* __restrict__ Aw, const __hip_bfloat16* __restrict__ Bw,
    float* __restrict__ S)
{
  __shared__ __hip_bfloat16 As[BM * BK];   // 16 KB, XOR-swizzled content
  __shared__ __hip_bfloat16 Bs[BN * BK];   // 16 KB

  const int t = threadIdx.x;
  const int lane = t & 63;
  const int wid = t >> 6;
  const int wrow = wid >> 1;   // 2x2 wave grid, each wave 64x64 output
  const int wcol = wid & 1;

  // XCD-aware swizzle: 4096 blocks, 8 XCDs, 4096%8==0 -> bijective
  const int bid = blockIdx.x;
  const int sw = (bid & 7) * 512 + (bid >> 3);
  const int tm = sw >> 6;      // / (N/BN)
  const int tn = sw & 63;

  const char* Ag = (const char*)(Aw + (size_t)tm * BM * D);
  const char* Bg = (const char*)(Bw + (size_t)tn * BN * D);

  // staging map: linear LDS dest chunk x -> inverse-swizzled global source
  // desired: LDS[swz(r*128+cb)] = T[r][cb], swz(a) = a ^ (((a>>7)&7)<<4) (involution)
  const char* aSrc[4]; const char* bSrc[4]; unsigned ldst[4];
  #pragma unroll
  for (int j = 0; j < 4; ++j) {
    const unsigned x = (unsigned)(t + j * 256) * 16u;
    const unsigned lin = x ^ (((x >> 7) & 7u) << 4);
    const unsigned r = lin >> 7, cb = lin & 127u;
    aSrc[j] = Ag + (size_t)r * (D * 2) + cb;
    bSrc[j] = Bg + (size_t)r * (D * 2) + cb;
    ldst[j] = x;
  }
  char* AsB = (char*)As; char* BsB = (char*)Bs;

  f32x4 acc[4][4] = {};

  for (int kt = 0; kt < D / BK; ++kt) {
    const int kb = kt * (BK * 2);
    #pragma unroll
    for (int j = 0; j < 4; ++j) {
      gload_lds16(aSrc[j] + kb, AsB + ldst[j]);
      gload_lds16(bSrc[j] + kb, BsB + ldst[j]);
    }
    __syncthreads();   // compiler emits vmcnt(0) drain before barrier
    #pragma unroll
    for (int ks = 0; ks < 2; ++ks) {
      bf16x8 af[4], bfr[4];
      #pragma unroll
      for (int m = 0; m < 4; ++m) {
        const int r = wrow * 64 + m * 16 + (lane & 15);
        const int cb = ks * 64 + ((lane >> 4) << 4);
        const int addr = ((r << 7) + cb) ^ ((r & 7) << 4);
        af[m] = *(const bf16x8*)(AsB + addr);
      }
      #pragma unroll
      for (int n = 0; n < 4; ++n) {
        const int r = wcol * 64 + n * 16 + (lane & 15);
        const int cb = ks * 64 + ((lane >> 4) << 4);
        const int addr = ((r << 7) + cb) ^ ((r & 7) << 4);
        bfr[n] = *(const bf16x8*)(BsB + addr);
      }
      #pragma unroll
      for (int m = 0; m < 4; ++m) {
        #pragma unroll
        for (int n = 0; n < 4; ++n) {
          acc[m][n] = __builtin_amdgcn_mfma_f32_16x16x32_bf16(
              af[m], bfr[n], acc[m][n], 0, 0, 0);
        }
      }
    }
    __syncthreads();
  }

  // epilogue: C/D layout col=lane&15, row=(lane>>4)*4+i (m89-verified)
  // logit <= ~10 so exp needs no max subtraction; sum over 128 cols of slab
  const int g = lane >> 4;
  const int c = lane & 15;
  #pragma unroll
  for (int m = 0; m < 4; ++m) {
    #pragma unroll
    for (int i = 0; i < 4; ++i) {
      float s = 0.0f;
      #pragma unroll
      for (int n = 0; n < 4; ++n) s += __expf(acc[m][n][i]);
      #pragma unroll
      for (int off = 1; off < 16; off <<= 1) s += __shfl_xor(s, off);
      if (c == 0) {
        const int row = tm * BM + wrow * 64 + m * 16 + g * 4 + i;
        atomicAdd(&S[row], s);
      }
    }
  }
}

// ---------------- Kernel C: loss = mean(log(S) - diag) ---------------------
__global__ __launch_bounds__(256) void UCR_loss(
    const float* __restrict__ S, const float* __restrict__ diag,
    float* __restrict__ out)
{
  float acc = 0.0f;
  for (int i = threadIdx.x; i < N; i += 256)
    acc += logf(S[i]) - diag[i];
  #pragma unroll
  for (int off = 1; off < 64; off <<= 1) acc += __shfl_xor(acc, off);
  __shared__ float r[4];
  if ((threadIdx.x & 63) == 0) r[threadIdx.x >> 6] = acc;
  __syncthreads();
  if (threadIdx.x == 0) out[0] = (r[0] + r[1] + r[2] + r[3]) * (1.0f / (float)N);
}

extern "C" void kernel_launch(void* const* d_in, const int* in_sizes, int n_in,
                              void* d_out, int out_size, void* d_ws, size_t ws_size,
                              hipStream_t stream)
{
  const float* inputs = (const float*)d_in[0];
  const float* noise  = (const float*)d_in[1];

  char* ws = (char*)d_ws;
  __hip_bfloat16* aB = (__hip_bfloat16*)ws;                       // 16 MB
  __hip_bfloat16* bB = aB + (size_t)N * D;                        // 16 MB
  float* S    = (float*)(bB + (size_t)N * D);                     // 32 KB
  float* diag = S + N;                                            // 32 KB

  hipMemsetAsync(S, 0, N * sizeof(float), stream);
  UCR_prep<<<N, 256, 0, stream>>>(inputs, noise, aB, bB, diag);
  UCR_gemm<<<(N / BM) * (N / BN), 256, 0, stream>>>(aB, bB, S);
  UCR_loss<<<1, 256, 0, stream>>>(S, diag, (float*)d_out);
}

// Round 2
// 309.059 us; speedup vs baseline: 1.2308x; 1.2308x over previous
//
#include <hip/hip_runtime.h>
#include <hip/hip_bf16.h>

#define N 8192
#define D 1024

static constexpr float TEMP = 0.1f;
static constexpr float KEEP = 0.9f;
static constexpr float EPSN = 1e-8f;

typedef __attribute__((ext_vector_type(8))) short bf16x8;
typedef __attribute__((ext_vector_type(4))) float f32x4;

__device__ __forceinline__ void gload_lds16(const void* gsrc, void* ldst) {
  __builtin_amdgcn_global_load_lds(
      (const __attribute__((address_space(1))) void*)gsrc,
      (__attribute__((address_space(3))) void*)ldst, 16, 0, 0);
}

// ---------------- Kernel A: norms + diag + bf16 convert (scales folded) ----
struct bf4pack { __hip_bfloat16 v[4]; };

__global__ __launch_bounds__(256) void UCR_prep(
    const float* __restrict__ inputs, const float* __restrict__ noise,
    __hip_bfloat16* __restrict__ aB, __hip_bfloat16* __restrict__ bB,
    float* __restrict__ diag)
{
  const int row = blockIdx.x;
  const int t = threadIdx.x;
  const float4 x = ((const float4*)(inputs + (size_t)row * D))[t];
  const float4 u = ((const float4*)(noise  + (size_t)row * D))[t];
  const float inv_keep = 1.0f / KEEP;
  float4 e;
  e.x = (u.x < KEEP) ? x.x * inv_keep : 0.0f;
  e.y = (u.y < KEEP) ? x.y * inv_keep : 0.0f;
  e.z = (u.z < KEEP) ? x.z * inv_keep : 0.0f;
  e.w = (u.w < KEEP) ? x.w * inv_keep : 0.0f;

  float sx  = x.x*x.x + x.y*x.y + x.z*x.z + x.w*x.w;
  float se  = e.x*e.x + e.y*e.y + e.z*e.z + e.w*e.w;
  float sxe = x.x*e.x + x.y*e.y + x.z*e.z + x.w*e.w;

  #pragma unroll
  for (int off = 1; off < 64; off <<= 1) {
    sx  += __shfl_xor(sx, off);
    se  += __shfl_xor(se, off);
    sxe += __shfl_xor(sxe, off);
  }
  __shared__ float red[3][4];
  const int wid = t >> 6, lane = t & 63;
  if (lane == 0) { red[0][wid] = sx; red[1][wid] = se; red[2][wid] = sxe; }
  __syncthreads();
  sx  = red[0][0] + red[0][1] + red[0][2] + red[0][3];
  se  = red[1][0] + red[1][1] + red[1][2] + red[1][3];
  sxe = red[2][0] + red[2][1] + red[2][2] + red[2][3];

  const float na = fmaxf(sqrtf(sx), EPSN);
  const float nb = fmaxf(sqrtf(se), EPSN);
  const float sa = 1.0f / (na * TEMP);
  const float sb = 1.0f / nb;
  if (t == 0) diag[row] = sxe / (na * nb * TEMP);

  bf4pack pa, pb;
  pa.v[0] = __float2bfloat16(x.x * sa); pa.v[1] = __float2bfloat16(x.y * sa);
  pa.v[2] = __float2bfloat16(x.z * sa); pa.v[3] = __float2bfloat16(x.w * sa);
  pb.v[0] = __float2bfloat16(e.x * sb); pb.v[1] = __float2bfloat16(e.y * sb);
  pb.v[2] = __float2bfloat16(e.z * sb); pb.v[3] = __float2bfloat16(e.w * sb);
  ((bf4pack*)(aB + (size_t)row * D))[t] = pa;
  ((bf4pack*)(bB + (size_t)row * D))[t] = pb;
}

// ---------------- Kernel B: 256x256-tile GEMM, 4-slot LDS ring, counted vmcnt
// logits[r][c] = sum_d aB[r][d]*bB[c][d]; S[r] += sum_c exp(logits[r][c])
// 8 waves (2 wm x 4 wn), per-wave output 128x64, BK=32, 32 K-tiles.
// LDS ring: 4 slots x (A 16KB + B 16KB) = 128 KB; prefetch 3 K-tiles deep.
__global__ __launch_bounds__(512, 1) void UCR_gemm(
    const __hip_bfloat16* __restrict__ Aw, const __hip_bfloat16* __restrict__ Bw,
    float* __restrict__ S)
{
  __shared__ char lds[131072];

  const int t = threadIdx.x;
  const int lane = t & 63;
  const int wid = t >> 6;      // 0..7
  const int wm = wid >> 2;     // 0..1  (row half)
  const int wn = wid & 3;      // 0..3  (col quarter)

  // XCD-aware swizzle: 1024 blocks, 1024 % 8 == 0 -> bijective
  const int bid = blockIdx.x;
  const int sw = (bid & 7) * 128 + (bid >> 3);
  const int tm = sw >> 5;      // / (N/256)
  const int tn = sw & 31;

  const char* Ag = (const char*)(Aw + (size_t)tm * 256 * D);
  const char* Bg = (const char*)(Bw + (size_t)tn * 256 * D);

  // staging map: linear LDS dest x -> inverse-swizzled global source.
  // LDS layout per operand: 256 rows x 32 K bf16 (64 B rows), swizzle
  // swz(a) = a ^ (((a>>6)&3)<<4)  (involution, modifies bits 4-5, key bits 6-7)
  const char* asrc[2]; const char* bsrc[2]; unsigned xs[2];
  #pragma unroll
  for (int c = 0; c < 2; ++c) {
    const unsigned x = (unsigned)(t + c * 512) * 16u;
    const unsigned lin = x ^ (((x >> 6) & 3u) << 4);
    asrc[c] = Ag + (size_t)(lin >> 6) * (D * 2) + (lin & 63u);
    bsrc[c] = Bg + (size_t)(lin >> 6) * (D * 2) + (lin & 63u);
    xs[c] = x;
  }

  f32x4 acc[8][4] = {};

  // prologue: stage K-tiles 0,1,2 into slots 0,1,2
  #pragma unroll
  for (int p = 0; p < 3; ++p) {
    char* L = lds + p * 32768;
    #pragma unroll
    for (int c = 0; c < 2; ++c) {
      gload_lds16(asrc[c] + p * 64, L + xs[c]);
      gload_lds16(bsrc[c] + p * 64, L + 16384 + xs[c]);
    }
  }

  const int rA0 = wm * 128 + (lane & 15);
  const int rB0 = wn * 64 + (lane & 15);
  const int cb0 = (lane >> 4) << 4;

  for (int kt = 0; kt < 32; ++kt) {
    // counted wait: steady state keeps 2 K-tiles (8 loads/wave) in flight
    if (kt < 30)       asm volatile("s_waitcnt vmcnt(8)" ::: "memory");
    else if (kt == 30) asm volatile("s_waitcnt vmcnt(4)" ::: "memory");
    else               asm volatile("s_waitcnt vmcnt(0)" ::: "memory");
    __builtin_amdgcn_s_barrier();  // all waves' K-tile kt slices landed;
                                   // slot (kt+3)&3 fully read in group kt-1

    if (kt < 29) {                 // stage K-tile kt+3 into its ring slot
      char* L = lds + ((kt + 3) & 3) * 32768;
      const int kb = (kt + 3) * 64;
      #pragma unroll
      for (int c = 0; c < 2; ++c) {
        gload_lds16(asrc[c] + kb, L + xs[c]);
        gload_lds16(bsrc[c] + kb, L + 16384 + xs[c]);
      }
    }

    const char* LA = lds + (kt & 3) * 32768;
    const char* LB = LA + 16384;
    bf16x8 aF[8], bF[4];
    #pragma unroll
    for (int m = 0; m < 8; ++m) {
      const int r = rA0 + m * 16;
      const int addr = (r << 6) + (cb0 ^ ((r & 3) << 4));
      aF[m] = *(const bf16x8*)(LA + addr);
    }
    #pragma unroll
    for (int n = 0; n < 4; ++n) {
      const int r = rB0 + n * 16;
      const int addr = (r << 6) + (cb0 ^ ((r & 3) << 4));
      bF[n] = *(const bf16x8*)(LB + addr);
    }

    __builtin_amdgcn_s_setprio(1);
    #pragma unroll
    for (int m = 0; m < 8; ++m)
      #pragma unroll
      for (int n = 0; n < 4; ++n)
        acc[m][n] = __builtin_amdgcn_mfma_f32_16x16x32_bf16(
            aF[m], bF[n], acc[m][n], 0, 0, 0);
    __builtin_amdgcn_s_setprio(0);
  }

  // epilogue: C/D frag layout col=lane&15, row=(lane>>4)*4+i
  const int g = lane >> 4;
  const int c = lane & 15;
  const int rowbase = tm * 256 + wm * 128;
  #pragma unroll
  for (int m = 0; m < 8; ++m) {
    #pragma unroll
    for (int i = 0; i < 4; ++i) {
      float s = 0.0f;
      #pragma unroll
      for (int n = 0; n < 4; ++n) s += __expf(acc[m][n][i]);
      #pragma unroll
      for (int off = 1; off < 16; off <<= 1) s += __shfl_xor(s, off);
      if (c == 0) atomicAdd(&S[rowbase + m * 16 + g * 4 + i], s);
    }
  }
}

// ---------------- Kernel C: loss = mean(log(S) - diag), 32-block version ----
__global__ __launch_bounds__(256) void UCR_loss(
    const float* __restrict__ S, const float* __restrict__ diag,
    float* __restrict__ out)
{
  const int i = blockIdx.x * 256 + threadIdx.x;
  float acc = logf(S[i]) - diag[i];
  #pragma unroll
  for (int off = 1; off < 64; off <<= 1) acc += __shfl_xor(acc, off);
  __shared__ float r[4];
  if ((threadIdx.x & 63) == 0) r[threadIdx.x >> 6] = acc;
  __syncthreads();
  if (threadIdx.x == 0)
    atomicAdd(out, (r[0] + r[1] + r[2] + r[3]) * (1.0f / (float)N));
}

extern "C" void kernel_launch(void* const* d_in, const int* in_sizes, int n_in,
                              void* d_out, int out_size, void* d_ws, size_t ws_size,
                              hipStream_t stream)
{
  const float* inputs = (const float*)d_in[0];
  const float* noise  = (const float*)d_in[1];

  char* ws = (char*)d_ws;
  __hip_bfloat16* aB = (__hip_bfloat16*)ws;                       // 16 MB
  __hip_bfloat16* bB = aB + (size_t)N * D;                        // 16 MB
  float* S    = (float*)(bB + (size_t)N * D);                     // 32 KB
  float* diag = S + N;                                            // 32 KB

  hipMemsetAsync(S, 0, N * sizeof(float), stream);
  hipMemsetAsync(d_out, 0, sizeof(float), stream);
  UCR_prep<<<N, 256, 0, stream>>>(inputs, noise, aB, bB, diag);
  UCR_gemm<<<(N / 256) * (N / 256), 512, 0, stream>>>(aB, bB, S);
  UCR_loss<<<N / 256, 256, 0, stream>>>(S, diag, (float*)d_out);
}

// Round 3
// 308.282 us; speedup vs baseline: 1.2339x; 1.0025x over previous
//
#include <hip/hip_runtime.h>
#include <hip/hip_bf16.h>

#define N 8192
#define D 1024

static constexpr float TEMP = 0.1f;
static constexpr float KEEP = 0.9f;
static constexpr float EPSN = 1e-8f;

typedef __attribute__((ext_vector_type(8))) short bf16x8;
typedef __attribute__((ext_vector_type(4))) float f32x4;

__device__ __forceinline__ void gload_lds16(const void* gsrc, void* ldst) {
  __builtin_amdgcn_global_load_lds(
      (const __attribute__((address_space(1))) void*)gsrc,
      (__attribute__((address_space(3))) void*)ldst, 16, 0, 0);
}

// ---------------- Kernel A: norms + diag + bf16 convert (scales folded) ----
struct bf4pack { __hip_bfloat16 v[4]; };

__global__ __launch_bounds__(256) void UCR_prep(
    const float* __restrict__ inputs, const float* __restrict__ noise,
    __hip_bfloat16* __restrict__ aB, __hip_bfloat16* __restrict__ bB,
    float* __restrict__ diag)
{
  const int row = blockIdx.x;
  const int t = threadIdx.x;
  const float4 x = ((const float4*)(inputs + (size_t)row * D))[t];
  const float4 u = ((const float4*)(noise  + (size_t)row * D))[t];
  const float inv_keep = 1.0f / KEEP;
  float4 e;
  e.x = (u.x < KEEP) ? x.x * inv_keep : 0.0f;
  e.y = (u.y < KEEP) ? x.y * inv_keep : 0.0f;
  e.z = (u.z < KEEP) ? x.z * inv_keep : 0.0f;
  e.w = (u.w < KEEP) ? x.w * inv_keep : 0.0f;

  float sx  = x.x*x.x + x.y*x.y + x.z*x.z + x.w*x.w;
  float se  = e.x*e.x + e.y*e.y + e.z*e.z + e.w*e.w;
  float sxe = x.x*e.x + x.y*e.y + x.z*e.z + x.w*e.w;

  #pragma unroll
  for (int off = 1; off < 64; off <<= 1) {
    sx  += __shfl_xor(sx, off);
    se  += __shfl_xor(se, off);
    sxe += __shfl_xor(sxe, off);
  }
  __shared__ float red[3][4];
  const int wid = t >> 6, lane = t & 63;
  if (lane == 0) { red[0][wid] = sx; red[1][wid] = se; red[2][wid] = sxe; }
  __syncthreads();
  sx  = red[0][0] + red[0][1] + red[0][2] + red[0][3];
  se  = red[1][0] + red[1][1] + red[1][2] + red[1][3];
  sxe = red[2][0] + red[2][1] + red[2][2] + red[2][3];

  const float na = fmaxf(sqrtf(sx), EPSN);
  const float nb = fmaxf(sqrtf(se), EPSN);
  const float sa = 1.0f / (na * TEMP);
  const float sb = 1.0f / nb;
  if (t == 0) diag[row] = sxe / (na * nb * TEMP);

  bf4pack pa, pb;
  pa.v[0] = __float2bfloat16(x.x * sa); pa.v[1] = __float2bfloat16(x.y * sa);
  pa.v[2] = __float2bfloat16(x.z * sa); pa.v[3] = __float2bfloat16(x.w * sa);
  pb.v[0] = __float2bfloat16(e.x * sb); pb.v[1] = __float2bfloat16(e.y * sb);
  pb.v[2] = __float2bfloat16(e.z * sb); pb.v[3] = __float2bfloat16(e.w * sb);
  ((bf4pack*)(aB + (size_t)row * D))[t] = pa;
  ((bf4pack*)(bB + (size_t)row * D))[t] = pb;
}

// ---------------- Kernel B: 256x256-tile GEMM, 4-slot LDS ring, counted vmcnt
// LDS rows are 64 B (BK=32). Bank period = 128 B = TWO rows, so the XOR
// swizzle must be keyed on r bits 1-2 (addr bits 7-8), NOT r bits 0-1:
//   swz(a) = a ^ (((a>>7)&3)<<4)   (involution; modifies bits 4-5)
// -> 8 consecutive rows cover all 8 (parity, 16B-slot) positions: 0 conflicts.
__global__ __launch_bounds__(512, 1) void UCR_gemm(
    const __hip_bfloat16* __restrict__ Aw, const __hip_bfloat16* __restrict__ Bw,
    float* __restrict__ S)
{
  __shared__ char lds[131072];

  const int t = threadIdx.x;
  const int lane = t & 63;
  const int wid = t >> 6;      // 0..7
  const int wm = wid >> 2;     // 0..1  (row half)
  const int wn = wid & 3;      // 0..3  (col quarter)

  // XCD-aware swizzle: 1024 blocks, 1024 % 8 == 0 -> bijective
  const int bid = blockIdx.x;
  const int sw = (bid & 7) * 128 + (bid >> 3);
  const int tm = sw >> 5;
  const int tn = sw & 31;

  const char* Ag = (const char*)(Aw + (size_t)tm * 256 * D);
  const char* Bg = (const char*)(Bw + (size_t)tn * 256 * D);

  // staging: linear LDS dest x -> inverse-swizzled global source (rule 21)
  const char* asrc[2]; const char* bsrc[2]; unsigned xs[2];
  #pragma unroll
  for (int c = 0; c < 2; ++c) {
    const unsigned x = (unsigned)(t + c * 512) * 16u;
    const unsigned lin = x ^ (((x >> 7) & 3u) << 4);
    asrc[c] = Ag + (size_t)(lin >> 6) * (D * 2) + (lin & 63u);
    bsrc[c] = Bg + (size_t)(lin >> 6) * (D * 2) + (lin & 63u);
    xs[c] = x;
  }

  f32x4 acc[8][4] = {};

  // prologue: stage K-tiles 0,1,2 into slots 0,1,2
  #pragma unroll
  for (int p = 0; p < 3; ++p) {
    char* L = lds + p * 32768;
    #pragma unroll
    for (int c = 0; c < 2; ++c) {
      gload_lds16(asrc[c] + p * 64, L + xs[c]);
      gload_lds16(bsrc[c] + p * 64, L + 16384 + xs[c]);
    }
  }

  const int rA0 = wm * 128 + (lane & 15);
  const int rB0 = wn * 64 + (lane & 15);
  const int cb0 = (lane >> 4) << 4;

  for (int kt = 0; kt < 32; ++kt) {
    // counted wait: steady state keeps 2 K-tiles (8 loads/wave) in flight
    if (kt < 30)       asm volatile("s_waitcnt vmcnt(8)" ::: "memory");
    else if (kt == 30) asm volatile("s_waitcnt vmcnt(4)" ::: "memory");
    else               asm volatile("s_waitcnt vmcnt(0)" ::: "memory");
    __builtin_amdgcn_s_barrier();  // tile kt visible to all waves;
                                   // slot (kt+3)&3 fully read in group kt-1

    if (kt < 29) {                 // stage K-tile kt+3 into its ring slot
      char* L = lds + ((kt + 3) & 3) * 32768;
      const int kb = (kt + 3) * 64;
      #pragma unroll
      for (int c = 0; c < 2; ++c) {
        gload_lds16(asrc[c] + kb, L + xs[c]);
        gload_lds16(bsrc[c] + kb, L + 16384 + xs[c]);
      }
    }

    const char* LA = lds + (kt & 3) * 32768;
    const char* LB = LA + 16384;
    bf16x8 aF[8], bF[4];
    #pragma unroll
    for (int m = 0; m < 8; ++m) {
      const int r = rA0 + m * 16;
      const int addr = (r << 6) + (cb0 ^ (((r >> 1) & 3) << 4));
      aF[m] = *(const bf16x8*)(LA + addr);
    }
    #pragma unroll
    for (int n = 0; n < 4; ++n) {
      const int r = rB0 + n * 16;
      const int addr = (r << 6) + (cb0 ^ (((r >> 1) & 3) << 4));
      bF[n] = *(const bf16x8*)(LB + addr);
    }

    __builtin_amdgcn_s_setprio(1);
    #pragma unroll
    for (int m = 0; m < 8; ++m)
      #pragma unroll
      for (int n = 0; n < 4; ++n)
        acc[m][n] = __builtin_amdgcn_mfma_f32_16x16x32_bf16(
            aF[m], bF[n], acc[m][n], 0, 0, 0);
    __builtin_amdgcn_s_setprio(0);
  }

  // epilogue: C/D frag layout col=lane&15, row=(lane>>4)*4+i
  const int g = lane >> 4;
  const int c = lane & 15;
  const int rowbase = tm * 256 + wm * 128;
  #pragma unroll
  for (int m = 0; m < 8; ++m) {
    #pragma unroll
    for (int i = 0; i < 4; ++i) {
      float s = 0.0f;
      #pragma unroll
      for (int n = 0; n < 4; ++n) s += __expf(acc[m][n][i]);
      #pragma unroll
      for (int off = 1; off < 16; off <<= 1) s += __shfl_xor(s, off);
      if (c == 0) atomicAdd(&S[rowbase + m * 16 + g * 4 + i], s);
    }
  }
}

// ---------------- Kernel C: loss = mean(log(S) - diag) ---------------------
__global__ __launch_bounds__(256) void UCR_loss(
    const float* __restrict__ S, const float* __restrict__ diag,
    float* __restrict__ out)
{
  const int i = blockIdx.x * 256 + threadIdx.x;
  float acc = logf(S[i]) - diag[i];
  #pragma unroll
  for (int off = 1; off < 64; off <<= 1) acc += __shfl_xor(acc, off);
  __shared__ float r[4];
  if ((threadIdx.x & 63) == 0) r[threadIdx.x >> 6] = acc;
  __syncthreads();
  if (threadIdx.x == 0)
    atomicAdd(out, (r[0] + r[1] + r[2] + r[3]) * (1.0f / (float)N));
}

extern "C" void kernel_launch(void* const* d_in, const int* in_sizes, int n_in,
                              void* d_out, int out_size, void* d_ws, size_t ws_size,
                              hipStream_t stream)
{
  const float* inputs = (const float*)d_in[0];
  const float* noise  = (const float*)d_in[1];

  char* ws = (char*)d_ws;
  __hip_bfloat16* aB = (__hip_bfloat16*)ws;                       // 16 MB
  __hip_bfloat16* bB = aB + (size_t)N * D;                        // 16 MB
  float* S    = (float*)(bB + (size_t)N * D);                     // 32 KB
  float* diag = S + N;                                            // 32 KB

  hipMemsetAsync(S, 0, N * sizeof(float), stream);
  hipMemsetAsync(d_out, 0, sizeof(float), stream);
  UCR_prep<<<N, 256, 0, stream>>>(inputs, noise, aB, bB, diag);
  UCR_gemm<<<(N / 256) * (N / 256), 512, 0, stream>>>(aB, bB, S);
  UCR_loss<<<N / 256, 256, 0, stream>>>(S, diag, (float*)d_out);
}

// Round 4
// 306.534 us; speedup vs baseline: 1.2409x; 1.0057x over previous
//
#include <hip/hip_runtime.h>
#include <hip/hip_bf16.h>

#define N 8192
#define D 1024

static constexpr float TEMP = 0.1f;
static constexpr float KEEP = 0.9f;
static constexpr float EPSN = 1e-8f;

typedef __attribute__((ext_vector_type(8))) short bf16x8;
typedef __attribute__((ext_vector_type(4))) float f32x4;

__device__ __forceinline__ void gload_lds16(const void* gsrc, void* ldst) {
  __builtin_amdgcn_global_load_lds(
      (const __attribute__((address_space(1))) void*)gsrc,
      (__attribute__((address_space(3))) void*)ldst, 16, 0, 0);
}

// ---------------- Kernel A: norms + diag + bf16 convert (scales folded) ----
struct bf4pack { __hip_bfloat16 v[4]; };

__global__ __launch_bounds__(256) void UCR_prep(
    const float* __restrict__ inputs, const float* __restrict__ noise,
    __hip_bfloat16* __restrict__ aB, __hip_bfloat16* __restrict__ bB,
    float* __restrict__ diag, float* __restrict__ S)
{
  const int row = blockIdx.x;
  const int t = threadIdx.x;
  const float4 x = ((const float4*)(inputs + (size_t)row * D))[t];
  const float4 u = ((const float4*)(noise  + (size_t)row * D))[t];
  const float inv_keep = 1.0f / KEEP;
  float4 e;
  e.x = (u.x < KEEP) ? x.x * inv_keep : 0.0f;
  e.y = (u.y < KEEP) ? x.y * inv_keep : 0.0f;
  e.z = (u.z < KEEP) ? x.z * inv_keep : 0.0f;
  e.w = (u.w < KEEP) ? x.w * inv_keep : 0.0f;

  float sx  = x.x*x.x + x.y*x.y + x.z*x.z + x.w*x.w;
  float se  = e.x*e.x + e.y*e.y + e.z*e.z + e.w*e.w;
  float sxe = x.x*e.x + x.y*e.y + x.z*e.z + x.w*e.w;

  #pragma unroll
  for (int off = 1; off < 64; off <<= 1) {
    sx  += __shfl_xor(sx, off);
    se  += __shfl_xor(se, off);
    sxe += __shfl_xor(sxe, off);
  }
  __shared__ float red[3][4];
  const int wid = t >> 6, lane = t & 63;
  if (lane == 0) { red[0][wid] = sx; red[1][wid] = se; red[2][wid] = sxe; }
  __syncthreads();
  sx  = red[0][0] + red[0][1] + red[0][2] + red[0][3];
  se  = red[1][0] + red[1][1] + red[1][2] + red[1][3];
  sxe = red[2][0] + red[2][1] + red[2][2] + red[2][3];

  const float na = fmaxf(sqrtf(sx), EPSN);
  const float nb = fmaxf(sqrtf(se), EPSN);
  const float sa = 1.0f / (na * TEMP);
  const float sb = 1.0f / nb;
  if (t == 0) { diag[row] = sxe / (na * nb * TEMP); S[row] = 0.0f; }

  bf4pack pa, pb;
  pa.v[0] = __float2bfloat16(x.x * sa); pa.v[1] = __float2bfloat16(x.y * sa);
  pa.v[2] = __float2bfloat16(x.z * sa); pa.v[3] = __float2bfloat16(x.w * sa);
  pb.v[0] = __float2bfloat16(e.x * sb); pb.v[1] = __float2bfloat16(e.y * sb);
  pb.v[2] = __float2bfloat16(e.z * sb); pb.v[3] = __float2bfloat16(e.w * sb);
  ((bf4pack*)(aB + (size_t)row * D))[t] = pa;
  ((bf4pack*)(bB + (size_t)row * D))[t] = pb;
}

// ---------------- Kernel B: 256x256 tile, BK=64, 8-phase schedule -----------
// 2 LDS buffers x (A[256][64] + B[256][64]) = 128 KB. Each K-tile = 4 phases
// of 16 MFMA; per-phase {ds_read subtile | stage half-tile | bar | lgkm0 |
// setprio MFMA setprio | bar}. vmcnt(4) once per K-tile (2 halves in flight).
// Stage deadness: A-halves staged P3/P4 (A reads done by P2 lgkm0); B-halves
// staged next tile's P1/P2 (B reads done by P3 lgkm0). Swizzle: 128 B rows,
// byte ^= (row&7)<<4, both-sides involution (linear gload dest + inv src).
__global__ __launch_bounds__(512, 2) void UCR_gemm(
    const __hip_bfloat16* __restrict__ Aw, const __hip_bfloat16* __restrict__ Bw,
    float* __restrict__ S)
{
  __shared__ char lds[131072];

  const int t = threadIdx.x;
  const int lane = t & 63;
  const int wid = t >> 6;      // 0..7
  const int wm = wid >> 2;     // 0..1  row half (128 rows)
  const int wn = wid & 3;      // 0..3  col quarter (64 cols)

  // XCD-aware swizzle: 1024 blocks, 1024 % 8 == 0 -> bijective
  const int bid = blockIdx.x;
  const int sw = (bid & 7) * 128 + (bid >> 3);
  const int tm = sw >> 5;
  const int tn = sw & 31;

  const char* Ag = (const char*)(Aw + (size_t)tm * 256 * D);
  const char* Bg = (const char*)(Bw + (size_t)tn * 256 * D);

  // staging map: linear LDS dest x -> inverse-swizzled global src (rule 21)
  const unsigned x0 = (unsigned)t * 16u, x1 = (unsigned)(t + 512) * 16u;
  const unsigned l0 = x0 ^ (((x0 >> 7) & 7u) << 4);
  const unsigned l1 = x1 ^ (((x1 >> 7) & 7u) << 4);
  const unsigned off0 = (l0 >> 7) * 2048u + (l0 & 127u);
  const unsigned off1 = (l1 >> 7) * 2048u + (l1 & 127u);

  // T: K-tile index; op: 0=A 1=B; h: 128-row half
#define STAGE(T, op, h) do {                                                 \
    const char* _g = (op) ? Bg : Ag;                                         \
    char* _L = lds + (((T) & 1) << 16) + ((op) << 15) + ((h) << 14);         \
    const size_t _go = (size_t)((h) * 128) * 2048 + (size_t)(T) * 128;       \
    gload_lds16(_g + _go + off0, _L + x0);                                   \
    gload_lds16(_g + _go + off1, _L + x1);                                   \
  } while (0)

  // fragment read map: row r, K-chunk cq of ks-half; swz key = r&7 = ln&7
  const int ln = lane & 15;
  const int cq = lane >> 4;
  const int swb = (ln & 7) << 4;
  const int colk0 = (cq * 16) ^ swb;
  const int colk1 = (64 + cq * 16) ^ swb;

  bf16x8 aLo[4][2], aHi[4][2], bLo[2][2], bHi[2][2];
  f32x4 acc[8][4] = {};

  // prologue: tile0 complete + tile1 A-halves in flight
  STAGE(0, 0, 0); STAGE(0, 0, 1); STAGE(0, 1, 0); STAGE(0, 1, 1);
  STAGE(1, 0, 0); STAGE(1, 0, 1);
  asm volatile("s_waitcnt vmcnt(4)" ::: "memory");
  __builtin_amdgcn_s_barrier();

  for (int kt = 0; kt < 16; ++kt) {
    const char* LA = lds + ((kt & 1) << 16);
    const char* LB = LA + 32768;
    const int rA = wm * 128 + ln;
    const int rB = wn * 64 + ln;

    // ---- P1: read aLo(8) + bLo(4); stage (kt+1).Bh0; MFMA Q0 (m0-3, n0-1)
    #pragma unroll
    for (int m = 0; m < 4; ++m) {
      const int rb = (rA + m * 16) << 7;
      aLo[m][0] = *(const bf16x8*)(LA + rb + colk0);
      aLo[m][1] = *(const bf16x8*)(LA + rb + colk1);
    }
    #pragma unroll
    for (int n = 0; n < 2; ++n) {
      const int rb = (rB + n * 16) << 7;
      bLo[n][0] = *(const bf16x8*)(LB + rb + colk0);
      bLo[n][1] = *(const bf16x8*)(LB + rb + colk1);
    }
    if (kt < 15) STAGE(kt + 1, 1, 0);
    asm volatile("s_waitcnt lgkmcnt(8)" ::: "memory");
    __builtin_amdgcn_s_barrier();
    asm volatile("s_waitcnt lgkmcnt(0)" ::: "memory");
    __builtin_amdgcn_sched_barrier(0);
    __builtin_amdgcn_s_setprio(1);
    #pragma unroll
    for (int ks = 0; ks < 2; ++ks)
      #pragma unroll
      for (int m = 0; m < 4; ++m)
        #pragma unroll
        for (int n = 0; n < 2; ++n)
          acc[m][n] = __builtin_amdgcn_mfma_f32_16x16x32_bf16(
              aLo[m][ks], bLo[n][ks], acc[m][n], 0, 0, 0);
    __builtin_amdgcn_s_setprio(0);
    __builtin_amdgcn_s_barrier();

    // ---- P2: read aHi(8); stage (kt+1).Bh1; MFMA Q1 (m4-7, n0-1)
    #pragma unroll
    for (int m = 0; m < 4; ++m) {
      const int rb = (rA + 64 + m * 16) << 7;
      aHi[m][0] = *(const bf16x8*)(LA + rb + colk0);
      aHi[m][1] = *(const bf16x8*)(LA + rb + colk1);
    }
    if (kt < 15) STAGE(kt + 1, 1, 1);
    __builtin_amdgcn_s_barrier();
    asm volatile("s_waitcnt lgkmcnt(0)" ::: "memory");
    __builtin_amdgcn_sched_barrier(0);
    __builtin_amdgcn_s_setprio(1);
    #pragma unroll
    for (int ks = 0; ks < 2; ++ks)
      #pragma unroll
      for (int m = 0; m < 4; ++m)
        #pragma unroll
        for (int n = 0; n < 2; ++n)
          acc[4 + m][n] = __builtin_amdgcn_mfma_f32_16x16x32_bf16(
              aHi[m][ks], bLo[n][ks], acc[4 + m][n], 0, 0, 0);
    __builtin_amdgcn_s_setprio(0);
    __builtin_amdgcn_s_barrier();

    // ---- P3: read bHi(4); stage (kt+2).Ah0; MFMA Q2 (m0-3, n2-3)
    #pragma unroll
    for (int n = 0; n < 2; ++n) {
      const int rb = (rB + 32 + n * 16) << 7;
      bHi[n][0] = *(const bf16x8*)(LB + rb + colk0);
      bHi[n][1] = *(const bf16x8*)(LB + rb + colk1);
    }
    if (kt < 14) STAGE(kt + 2, 0, 0);
    __builtin_amdgcn_s_barrier();
    asm volatile("s_waitcnt lgkmcnt(0)" ::: "memory");
    __builtin_amdgcn_sched_barrier(0);
    __builtin_amdgcn_s_setprio(1);
    #pragma unroll
    for (int ks = 0; ks < 2; ++ks)
      #pragma unroll
      for (int m = 0; m < 4; ++m)
        #pragma unroll
        for (int n = 0; n < 2; ++n)
          acc[m][2 + n] = __builtin_amdgcn_mfma_f32_16x16x32_bf16(
              aLo[m][ks], bHi[n][ks], acc[m][2 + n], 0, 0, 0);
    __builtin_amdgcn_s_setprio(0);
    __builtin_amdgcn_s_barrier();

    // ---- P4: stage (kt+2).Ah1; MFMA Q3 (m4-7, n2-3); boundary vmcnt + bar
    if (kt < 14) STAGE(kt + 2, 0, 1);
    __builtin_amdgcn_s_setprio(1);
    #pragma unroll
    for (int ks = 0; ks < 2; ++ks)
      #pragma unroll
      for (int m = 0; m < 4; ++m)
        #pragma unroll
        for (int n = 0; n < 2; ++n)
          acc[4 + m][2 + n] = __builtin_amdgcn_mfma_f32_16x16x32_bf16(
              aHi[m][ks], bHi[n][ks], acc[4 + m][2 + n], 0, 0, 0);
    __builtin_amdgcn_s_setprio(0);
    if (kt < 14)       asm volatile("s_waitcnt vmcnt(4)" ::: "memory");
    else if (kt == 14) asm volatile("s_waitcnt vmcnt(0)" ::: "memory");
    if (kt < 15) __builtin_amdgcn_s_barrier();
  }
#undef STAGE

  // epilogue: C/D frag layout col=lane&15, row=(lane>>4)*4+i
  const int g = lane >> 4;
  const int c = lane & 15;
  const int rowbase = tm * 256 + wm * 128;
  #pragma unroll
  for (int m = 0; m < 8; ++m) {
    #pragma unroll
    for (int i = 0; i < 4; ++i) {
      float s = 0.0f;
      #pragma unroll
      for (int n = 0; n < 4; ++n) s += __expf(acc[m][n][i]);
      #pragma unroll
      for (int off = 1; off < 16; off <<= 1) s += __shfl_xor(s, off);
      if (c == 0) atomicAdd(&S[rowbase + m * 16 + g * 4 + i], s);
    }
  }
}

// ---------------- Kernel C: loss = mean(log(S) - diag), single block -------
__global__ __launch_bounds__(256) void UCR_loss(
    const float* __restrict__ S, const float* __restrict__ diag,
    float* __restrict__ out)
{
  float acc = 0.0f;
  for (int i = threadIdx.x; i < N; i += 256)
    acc += logf(S[i]) - diag[i];
  #pragma unroll
  for (int off = 1; off < 64; off <<= 1) acc += __shfl_xor(acc, off);
  __shared__ float r[4];
  if ((threadIdx.x & 63) == 0) r[threadIdx.x >> 6] = acc;
  __syncthreads();
  if (threadIdx.x == 0)
    out[0] = (r[0] + r[1] + r[2] + r[3]) * (1.0f / (float)N);
}

extern "C" void kernel_launch(void* const* d_in, const int* in_sizes, int n_in,
                              void* d_out, int out_size, void* d_ws, size_t ws_size,
                              hipStream_t stream)
{
  const float* inputs = (const float*)d_in[0];
  const float* noise  = (const float*)d_in[1];

  char* ws = (char*)d_ws;
  __hip_bfloat16* aB = (__hip_bfloat16*)ws;                       // 16 MB
  __hip_bfloat16* bB = aB + (size_t)N * D;                        // 16 MB
  float* S    = (float*)(bB + (size_t)N * D);                     // 32 KB
  float* diag = S + N;                                            // 32 KB

  UCR_prep<<<N, 256, 0, stream>>>(inputs, noise, aB, bB, diag, S);
  UCR_gemm<<<(N / 256) * (N / 256), 512, 0, stream>>>(aB, bB, S);
  UCR_loss<<<1, 256, 0, stream>>>(S, diag, (float*)d_out);
}